// Round 1
// baseline (103.892 us; speedup 1.0000x reference)
//
#include <hip/hip_runtime.h>

// Problem: B=131072 trajectory points (D=16, fp32), K=256 centers (fp32).
// Outputs concatenated in d_out (float32): [B] argmin indices, then [B,16] offsets.
//
// Strategy:
//  - prep kernel: n2c[k][d] = -2*centers[k][d], c2[k] = sum_d centers[k][d]^2  (in d_ws)
//  - main kernel: one thread per point; score(k) = c2[k] + sum_d x[d]*n2c[k][d]
//    == c2 - 2*x.c  (x2 constant per point, irrelevant for argmin; matches the
//    reference's expanded-form numerics).
//  - centers are read with a wave-uniform index k -> compiler emits s_load via
//    the scalar K$ (free broadcast), avoiding the LDS-broadcast bottleneck
//    (ds_read_b128 pipe would cost ~20us; VALU bound is ~8us).

constexpr int Bn = 131072;
constexpr int Kn = 256;
constexpr int Dn = 16;

__global__ __launch_bounds__(256) void prep_kernel(
    const float* __restrict__ centers, float* __restrict__ n2c,
    float* __restrict__ c2) {
  int t = blockIdx.x * 256 + threadIdx.x;
  if (t < Kn * Dn) n2c[t] = -2.0f * centers[t];
  if (t < Kn) {
    const float* c = centers + t * Dn;
    float s = 0.0f;
#pragma unroll
    for (int d = 0; d < Dn; ++d) s = fmaf(c[d], c[d], s);
    c2[t] = s;
  }
}

__global__ __launch_bounds__(256) void assign_kernel(
    const float* __restrict__ traj, const float* __restrict__ centers,
    const float* __restrict__ n2c, const float* __restrict__ c2,
    float* __restrict__ out) {
  const int b = blockIdx.x * 256 + threadIdx.x;

  // Load this point's 16 coords with 4x dwordx4.
  const float4* xp = reinterpret_cast<const float4*>(traj + (size_t)b * Dn);
  float4 v0 = xp[0], v1 = xp[1], v2 = xp[2], v3 = xp[3];
  float x[Dn] = {v0.x, v0.y, v0.z, v0.w, v1.x, v1.y, v1.z, v1.w,
                 v2.x, v2.y, v2.z, v2.w, v3.x, v3.y, v3.z, v3.w};

  float best = __builtin_inff();
  int bi = 0;

  // k is wave-uniform -> n2c/c2 accesses become s_load (scalar cache broadcast).
  // unroll 4 gives 4 independent FMA chains to cover the 4-cyc FMA latency.
#pragma unroll 4
  for (int k = 0; k < Kn; ++k) {
    const float* c = n2c + k * Dn;
    float acc = c2[k];
#pragma unroll
    for (int d = 0; d < Dn; ++d) acc = fmaf(x[d], c[d], acc);
    // strict < keeps the first (lowest-k) minimum, matching jnp.argmin ties.
    if (acc < best) { best = acc; bi = k; }
  }

  // Output 0: index as float32.
  out[b] = (float)bi;

  // Output 1: offset = x - centers[bi] (exact fp32 sub, per-lane vector loads;
  // 16KB of centers is L1/L2 resident).
  const float* cb = centers + bi * Dn;
  float4 o0 = make_float4(x[0] - cb[0], x[1] - cb[1], x[2] - cb[2], x[3] - cb[3]);
  float4 o1 = make_float4(x[4] - cb[4], x[5] - cb[5], x[6] - cb[6], x[7] - cb[7]);
  float4 o2 = make_float4(x[8] - cb[8], x[9] - cb[9], x[10] - cb[10], x[11] - cb[11]);
  float4 o3 = make_float4(x[12] - cb[12], x[13] - cb[13], x[14] - cb[14], x[15] - cb[15]);
  float4* op = reinterpret_cast<float4*>(out + Bn + (size_t)b * Dn);
  op[0] = o0; op[1] = o1; op[2] = o2; op[3] = o3;
}

extern "C" void kernel_launch(void* const* d_in, const int* in_sizes, int n_in,
                              void* d_out, int out_size, void* d_ws, size_t ws_size,
                              hipStream_t stream) {
  const float* traj = (const float*)d_in[0];     // [131072, 16]
  const float* centers = (const float*)d_in[1];  // [256, 16]
  float* out = (float*)d_out;                    // [131072] idx ++ [131072*16] offsets

  float* n2c = (float*)d_ws;                     // 4096 floats
  float* c2 = n2c + Kn * Dn;                     // 256 floats

  prep_kernel<<<16, 256, 0, stream>>>(centers, n2c, c2);
  assign_kernel<<<Bn / 256, 256, 0, stream>>>(traj, centers, n2c, c2, out);
}

// Round 2
// 79.937 us; speedup vs baseline: 1.2997x; 1.2997x over previous
//
#include <hip/hip_runtime.h>

// B=131072 points (D=16 fp32), K=256 centers. Out (fp32): [B] argmin idx ++ [B,16] offsets.
//
// Single fused kernel. Block = 256 thr = 4 waves, handles 64 points.
//   Stage 1: block computes c2[k] = ||centers[k]||^2 into LDS (thread t -> center t).
//   Stage 2: wave w scans centers [64w, 64w+64) for all 64 points (lane = point).
//            k is wave-uniform (readfirstlane) -> center rows come via s_load
//            (scalar K$ broadcast, round-1-verified: SGPR=96). score = c2[k] - 2*x.c
//            via acc = c2s[k]; fma(y[d]=-2x[d], c[d]). Matches reference's
//            expanded-form argmin (x2 is per-point constant).
//   Stage 3: wave 0 reduces the 4 chunk winners per point (ascending chunk +
//            strict < keeps lowest-k on ties, matching jnp.argmin), writes idx;
//            then all 256 threads store offsets coalesced (thread t -> point
//            t>>2, quarter t&3, 16B each; traj/centers re-reads are L1-hot).

constexpr int Bn = 131072;
constexpr int Kn = 256;
constexpr int Dn = 16;
constexpr int PTS = 64;       // points per block
constexpr int NW = 4;         // waves per block == K chunks
constexpr int KC = Kn / NW;   // 64 centers per wave

__global__ __launch_bounds__(256, 8) void kmeans_kernel(
    const float* __restrict__ traj, const float* __restrict__ centers,
    float* __restrict__ out) {
  __shared__ float c2s[Kn];
  __shared__ float sbest[NW * PTS];
  __shared__ int sbi[NW * PTS];
  __shared__ int swin[PTS];

  const int t = threadIdx.x;
  const int blk = blockIdx.x;

  // ---- Stage 1: c2 into LDS (thread t handles center t; coalesced 64B/lane).
  {
    const float4* cp = reinterpret_cast<const float4*>(centers + t * Dn);
    float4 a = cp[0], b = cp[1], c = cp[2], d = cp[3];
    float s = 0.0f;
    s = fmaf(a.x, a.x, s); s = fmaf(a.y, a.y, s);
    s = fmaf(a.z, a.z, s); s = fmaf(a.w, a.w, s);
    s = fmaf(b.x, b.x, s); s = fmaf(b.y, b.y, s);
    s = fmaf(b.z, b.z, s); s = fmaf(b.w, b.w, s);
    s = fmaf(c.x, c.x, s); s = fmaf(c.y, c.y, s);
    s = fmaf(c.z, c.z, s); s = fmaf(c.w, c.w, s);
    s = fmaf(d.x, d.x, s); s = fmaf(d.y, d.y, s);
    s = fmaf(d.z, d.z, s); s = fmaf(d.w, d.w, s);
    c2s[t] = s;
  }
  __syncthreads();

  // ---- Stage 2: wave-uniform K chunk scan.
  const int w = __builtin_amdgcn_readfirstlane(t >> 6);  // wave id, SGPR
  const int l = t & 63;                                  // lane = point in block
  const int p = blk * PTS + l;

  float y[Dn];
  {
    const float4* xp = reinterpret_cast<const float4*>(traj + (size_t)p * Dn);
    float4 v0 = xp[0], v1 = xp[1], v2 = xp[2], v3 = xp[3];
    y[0] = -2.0f * v0.x; y[1] = -2.0f * v0.y; y[2] = -2.0f * v0.z; y[3] = -2.0f * v0.w;
    y[4] = -2.0f * v1.x; y[5] = -2.0f * v1.y; y[6] = -2.0f * v1.z; y[7] = -2.0f * v1.w;
    y[8] = -2.0f * v2.x; y[9] = -2.0f * v2.y; y[10] = -2.0f * v2.z; y[11] = -2.0f * v2.w;
    y[12] = -2.0f * v3.x; y[13] = -2.0f * v3.y; y[14] = -2.0f * v3.z; y[15] = -2.0f * v3.w;
  }

  float best = __builtin_inff();
  int bi = 0;
  const int k0 = w * KC;
#pragma unroll 4
  for (int kk = 0; kk < KC; ++kk) {
    const int k = k0 + kk;
    const float* cr = centers + k * Dn;  // wave-uniform -> s_load
    float acc = c2s[k];
#pragma unroll
    for (int d = 0; d < Dn; ++d) acc = fmaf(y[d], cr[d], acc);
    if (acc < best) { best = acc; bi = k; }  // strict <: lowest k wins ties
  }
  sbest[w * PTS + l] = best;
  sbi[w * PTS + l] = bi;
  __syncthreads();

  // ---- Stage 3a: wave 0 reduces 4 chunks per point (ascending chunk order
  // + strict < keeps the lowest-k winner on exact ties).
  if (t < PTS) {
    float b0 = sbest[t];
    int i0 = sbi[t];
#pragma unroll
    for (int ww = 1; ww < NW; ++ww) {
      float b1 = sbest[ww * PTS + t];
      int i1 = sbi[ww * PTS + t];
      if (b1 < b0) { b0 = b1; i0 = i1; }
    }
    swin[t] = i0;
    out[blk * PTS + t] = (float)i0;  // idx output (fp32 buffer)
  }
  __syncthreads();

  // ---- Stage 3b: coalesced offset store. Thread t -> point t>>2, quarter t&3.
  {
    const int pb = t >> 2, q = t & 3;
    const int pt = blk * PTS + pb;
    const int win = swin[pb];
    float4 xv = reinterpret_cast<const float4*>(traj + (size_t)pt * Dn)[q];  // L1-hot
    float4 cv = reinterpret_cast<const float4*>(centers + (size_t)win * Dn)[q];
    float4 o = make_float4(xv.x - cv.x, xv.y - cv.y, xv.z - cv.z, xv.w - cv.w);
    reinterpret_cast<float4*>(out + Bn)[(size_t)pt * 4 + q] = o;
  }
}

extern "C" void kernel_launch(void* const* d_in, const int* in_sizes, int n_in,
                              void* d_out, int out_size, void* d_ws, size_t ws_size,
                              hipStream_t stream) {
  const float* traj = (const float*)d_in[0];     // [131072, 16]
  const float* centers = (const float*)d_in[1];  // [256, 16]
  float* out = (float*)d_out;                    // [131072] idx ++ [131072*16] offsets
  kmeans_kernel<<<Bn / PTS, 256, 0, stream>>>(traj, centers, out);
}

// Round 5
// 74.205 us; speedup vs baseline: 1.4001x; 1.0772x over previous
//
#include <hip/hip_runtime.h>

// B=131072 points (D=16 fp32), K=256 centers. Out (fp32): [B] argmin idx ++ [B,16] offsets.
//
// 2 points per lane via packed fp32. The packed FMA is written as plain
// vector arithmetic (y*c + acc on an ext_vector_type(2) float) — clang fuses
// it to llvm.fma.v2f32 -> v_pk_fma_f32 under HIP's default -ffp-contract=fast.
// (Round 3/4 used __builtin_elementwise_fma and hit container failures twice;
// this version removes the only non-standard construct.)
//
//   Block = 256 thr = 4 waves, handles 128 points (lane l owns points
//   blk*128+l and blk*128+64+l). Wave w scans centers [64w,64w+64);
//   k is wave-uniform -> center row arrives via s_load (scalar K$ broadcast),
//   and pk_fma takes the center element as its one SGPR operand (broadcast).
//   score = c2[k] - 2*x.c (x2 per-point constant, argmin-invariant; strict <
//   => lowest-k tie-break like jnp.argmin). Cross-wave winner reduction via
//   LDS, then coalesced float4 offset stores (traj/centers re-reads L1-hot).

constexpr int Bn = 131072;
constexpr int Kn = 256;
constexpr int Dn = 16;
constexpr int PTS = 128;      // points per block (2 per lane)
constexpr int NW = 4;         // waves per block == K chunks
constexpr int KC = Kn / NW;   // 64 centers per wave

typedef float v2f __attribute__((ext_vector_type(2)));

__global__ __launch_bounds__(256, 8) void kmeans_kernel(
    const float* __restrict__ traj, const float* __restrict__ centers,
    float* __restrict__ out) {
  __shared__ float c2s[Kn];
  __shared__ float sbest[NW * PTS];
  __shared__ int sbi[NW * PTS];
  __shared__ int swin[PTS];

  const int t = threadIdx.x;
  const int blk = blockIdx.x;

  // ---- Stage 1: c2[k] = ||centers[k]||^2 into LDS (thread t -> center t).
  {
    const float4* cp = reinterpret_cast<const float4*>(centers + t * Dn);
    float4 a = cp[0], b = cp[1], c = cp[2], d = cp[3];
    float s = 0.0f;
    s = fmaf(a.x, a.x, s); s = fmaf(a.y, a.y, s);
    s = fmaf(a.z, a.z, s); s = fmaf(a.w, a.w, s);
    s = fmaf(b.x, b.x, s); s = fmaf(b.y, b.y, s);
    s = fmaf(b.z, b.z, s); s = fmaf(b.w, b.w, s);
    s = fmaf(c.x, c.x, s); s = fmaf(c.y, c.y, s);
    s = fmaf(c.z, c.z, s); s = fmaf(c.w, c.w, s);
    s = fmaf(d.x, d.x, s); s = fmaf(d.y, d.y, s);
    s = fmaf(d.z, d.z, s); s = fmaf(d.w, d.w, s);
    c2s[t] = s;
  }
  __syncthreads();

  const int w = __builtin_amdgcn_readfirstlane(t >> 6);  // wave id (SGPR)
  const int l = t & 63;                                  // lane
  const int p0 = blk * PTS + l;        // this lane's point 0
  const int p1 = p0 + 64;              // this lane's point 1

  // ---- Load y = -2*x for both points, packed {pt0, pt1} per dim.
  v2f y[Dn];
  {
    const float4* xa = reinterpret_cast<const float4*>(traj + (size_t)p0 * Dn);
    const float4* xb = reinterpret_cast<const float4*>(traj + (size_t)p1 * Dn);
#pragma unroll
    for (int q = 0; q < 4; ++q) {
      float4 a = xa[q], b = xb[q];
      y[q * 4 + 0] = (v2f){-2.0f * a.x, -2.0f * b.x};
      y[q * 4 + 1] = (v2f){-2.0f * a.y, -2.0f * b.y};
      y[q * 4 + 2] = (v2f){-2.0f * a.z, -2.0f * b.z};
      y[q * 4 + 3] = (v2f){-2.0f * a.w, -2.0f * b.w};
    }
  }

  float best0 = __builtin_inff(), best1 = __builtin_inff();
  int bi0 = 0, bi1 = 0;
  const int k0 = w * KC;
#pragma unroll 4
  for (int kk = 0; kk < KC; ++kk) {
    const int k = k0 + kk;
    const float* cr = centers + k * Dn;  // wave-uniform -> s_load_dwordx16
    const float c2k = c2s[k];
    v2f acc = (v2f){c2k, c2k};
#pragma unroll
    for (int d = 0; d < Dn; ++d) {
      const float c = cr[d];             // SGPR; broadcast into both halves
      acc = y[d] * (v2f){c, c} + acc;    // contracts to v_pk_fma_f32
    }
    if (acc.x < best0) { best0 = acc.x; bi0 = k; }  // strict <: lowest-k ties
    if (acc.y < best1) { best1 = acc.y; bi1 = k; }
  }
  sbest[w * PTS + l] = best0;
  sbi[w * PTS + l] = bi0;
  sbest[w * PTS + 64 + l] = best1;
  sbi[w * PTS + 64 + l] = bi1;
  __syncthreads();

  // ---- Cross-wave reduction: threads 0..127, one per point. Ascending chunk
  // order + strict < keeps the lowest-k winner on exact ties.
  if (t < PTS) {
    float b0 = sbest[t];
    int i0 = sbi[t];
#pragma unroll
    for (int ww = 1; ww < NW; ++ww) {
      float b1 = sbest[ww * PTS + t];
      int i1 = sbi[ww * PTS + t];
      if (b1 < b0) { b0 = b1; i0 = i1; }
    }
    swin[t] = i0;
    out[blk * PTS + t] = (float)i0;  // idx output (fp32 buffer), coalesced
  }
  __syncthreads();

  // ---- Coalesced offset stores: 128 points x 4 quarters = 512 float4 ops,
  // 2 iterations over 256 threads.
#pragma unroll
  for (int it = 0; it < 2; ++it) {
    const int id = it * 256 + t;
    const int pb = id >> 2, q = id & 3;
    const int pt = blk * PTS + pb;
    const int win = swin[pb];
    float4 xv = reinterpret_cast<const float4*>(traj + (size_t)pt * Dn)[q];  // L1-hot
    float4 cv = reinterpret_cast<const float4*>(centers + (size_t)win * Dn)[q];
    float4 o = make_float4(xv.x - cv.x, xv.y - cv.y, xv.z - cv.z, xv.w - cv.w);
    reinterpret_cast<float4*>(out + Bn)[(size_t)pt * 4 + q] = o;
  }
}

extern "C" void kernel_launch(void* const* d_in, const int* in_sizes, int n_in,
                              void* d_out, int out_size, void* d_ws, size_t ws_size,
                              hipStream_t stream) {
  (void)in_sizes; (void)n_in; (void)out_size; (void)d_ws; (void)ws_size;
  const float* traj = (const float*)d_in[0];     // [131072, 16]
  const float* centers = (const float*)d_in[1];  // [256, 16]
  float* out = (float*)d_out;                    // [131072] idx ++ [131072*16] offsets
  kmeans_kernel<<<Bn / PTS, 256, 0, stream>>>(traj, centers, out);
}